// Round 15
// baseline (392.550 us; speedup 1.0000x reference)
//
#include <hip/hip_runtime.h>
#include <hip/hip_bf16.h>

#define HID 2048
#define NH 32
#define NKV 8
#define HD 64
#define BB 2
#define SS_ 2048
#define MM (BB * SS_)     // 4096 rows

#define QT 256            // q rows per attn block (8 waves x 32)
#define KT 64             // kv rows per tile
#define LDK 72            // padded stride (u16) for Ks
#define LDV 68            // padded stride (u16) for Vt
#define LDO 66            // padded stride (u16) for Ot

typedef unsigned short u16;
typedef __attribute__((ext_vector_type(8)))  short bf16x8;
typedef __attribute__((ext_vector_type(4)))  float f32x4;
typedef __attribute__((ext_vector_type(16))) float f32x16;

__device__ __forceinline__ u16 f2bf(float f) {
    union { float f; unsigned int i; } v; v.f = f;
    unsigned int lsb = (v.i >> 16) & 1u;
    v.i += 0x7fffu + lsb;               // round-to-nearest-even
    return (u16)(v.i >> 16);
}
// RTN pack (epilogue only): LOW u16 = lo
__device__ __forceinline__ unsigned int pack_bf2(float lo, float hi) {
    return ((unsigned int)f2bf(hi) << 16) | (unsigned int)f2bf(lo);
}
// 1-instr RTZ pack via v_perm_b32 byte-select: D = {hi[31:16], lo[31:16]}
__device__ __forceinline__ unsigned int pack_rtz(float lo, float hi) {
    return __builtin_amdgcn_perm(__float_as_uint(hi), __float_as_uint(lo), 0x07060302u);
}

// ---------------------------------------------------------------------------
// K0a: straight fp32 -> bf16 convert (X)
// ---------------------------------------------------------------------------
__global__ __launch_bounds__(256) void cvt_kernel(
    const float* __restrict__ in, u16* __restrict__ out, int n4)
{
    const int i = blockIdx.x * 256 + threadIdx.x;
    if (i < n4) {
        float4 f = ((const float4*)in)[i];
        ushort4 r;
        r.x = f2bf(f.x); r.y = f2bf(f.y); r.z = f2bf(f.z); r.w = f2bf(f.w);
        ((ushort4*)out)[i] = r;
    }
}

// ---------------------------------------------------------------------------
// K0b: transpose-convert weights: fp32 [K][N] -> bf16 [N][K].
// ---------------------------------------------------------------------------
__global__ __launch_bounds__(256) void tw_kernel(
    const float* __restrict__ Wq, const float* __restrict__ Wk,
    const float* __restrict__ Wv, const float* __restrict__ Wo,
    u16* __restrict__ Tq, u16* __restrict__ Tk,
    u16* __restrict__ Tv, u16* __restrict__ To)
{
    __shared__ float tile[64][65];
    const int by = blockIdx.y;
    const float* W; u16* T; int N, n0;
    if (by < 32)      { W = Wq; T = Tq; N = 2048; n0 = by * 64; }
    else if (by < 40) { W = Wk; T = Tk; N = 512;  n0 = (by - 32) * 64; }
    else if (by < 48) { W = Wv; T = Tv; N = 512;  n0 = (by - 40) * 64; }
    else              { W = Wo; T = To; N = 2048; n0 = (by - 48) * 64; }
    const int k0 = blockIdx.x * 64;
    const int r  = threadIdx.x >> 2;
    const int c0 = (threadIdx.x & 3) << 4;
    #pragma unroll
    for (int u = 0; u < 4; ++u) {
        float4 f = *(const float4*)&W[(size_t)(k0 + r) * N + n0 + c0 + u * 4];
        tile[r][c0 + u * 4 + 0] = f.x; tile[r][c0 + u * 4 + 1] = f.y;
        tile[r][c0 + u * 4 + 2] = f.z; tile[r][c0 + u * 4 + 3] = f.w;
    }
    __syncthreads();
    #pragma unroll
    for (int u = 0; u < 4; ++u) {
        ushort4 o;
        o.x = f2bf(tile[c0 + u * 4 + 0][r]);
        o.y = f2bf(tile[c0 + u * 4 + 1][r]);
        o.z = f2bf(tile[c0 + u * 4 + 2][r]);
        o.w = f2bf(tile[c0 + u * 4 + 3][r]);
        *(ushort4*)&T[(size_t)(n0 + r) * HID + k0 + c0 + u * 4] = o;
    }
}

// ---------------------------------------------------------------------------
// K1: QKV projection, bf16 MFMA (16x16x32), 128x128x32 tile (round-11 form).
// ---------------------------------------------------------------------------
__global__ __launch_bounds__(256) void proj_kernel(
    const u16* __restrict__ Xb,
    const u16* __restrict__ Tq, const u16* __restrict__ Tk, const u16* __restrict__ Tv,
    const float* __restrict__ bq, const float* __restrict__ bk, const float* __restrict__ bv,
    u16* __restrict__ qo, u16* __restrict__ ko, u16* __restrict__ vo)
{
    __shared__ u16 Al[128][36];
    __shared__ u16 Bl[128][36];
    const int tid = threadIdx.x;
    const int w = tid >> 6, l15 = tid & 15, lg = (tid & 63) >> 4;
    const int wr = w >> 1, wc = w & 1;
    const int m0 = blockIdx.x * 128;
    const int n0 = blockIdx.y * 128;

    const u16* Bt; const float* bias; u16* dst; int nh, nb;
    if (n0 < 2048)      { Bt = Tq + (size_t)n0 * HID;          bias = bq + n0;          dst = qo; nh = NH;  nb = n0; }
    else if (n0 < 2560) { Bt = Tk + (size_t)(n0 - 2048) * HID; bias = bk + (n0 - 2048); dst = ko; nh = NKV; nb = n0 - 2048; }
    else                { Bt = Tv + (size_t)(n0 - 2560) * HID; bias = bv + (n0 - 2560); dst = vo; nh = NKV; nb = n0 - 2560; }

    const int sm = tid >> 2;
    const int sk = (tid & 3) << 3;

    f32x4 acc[4][4] = {};
    for (int k0 = 0; k0 < HID; k0 += 32) {
        bf16x8 a0 = *(const bf16x8*)&Xb[(size_t)(m0 + sm) * HID + k0 + sk];
        bf16x8 a1 = *(const bf16x8*)&Xb[(size_t)(m0 + 64 + sm) * HID + k0 + sk];
        bf16x8 b0 = *(const bf16x8*)&Bt[(size_t)sm * HID + k0 + sk];
        bf16x8 b1 = *(const bf16x8*)&Bt[(size_t)(64 + sm) * HID + k0 + sk];
        __syncthreads();
        *(bf16x8*)&Al[sm][sk]      = a0;
        *(bf16x8*)&Al[64 + sm][sk] = a1;
        *(bf16x8*)&Bl[sm][sk]      = b0;
        *(bf16x8*)&Bl[64 + sm][sk] = b1;
        __syncthreads();
        bf16x8 af[4], bfr[4];
        #pragma unroll
        for (int i = 0; i < 4; ++i) {
            af[i]  = *(const bf16x8*)&Al[wr * 64 + i * 16 + l15][lg * 8];
            bfr[i] = *(const bf16x8*)&Bl[wc * 64 + i * 16 + l15][lg * 8];
        }
        #pragma unroll
        for (int mf = 0; mf < 4; ++mf)
            #pragma unroll
            for (int nf = 0; nf < 4; ++nf)
                acc[mf][nf] = __builtin_amdgcn_mfma_f32_16x16x32_bf16(af[mf], bfr[nf], acc[mf][nf], 0, 0, 0);
    }

    #pragma unroll
    for (int nf = 0; nf < 4; ++nf) {
        const int cl = nb + wc * 64 + nf * 16 + l15;
        const int hh = cl >> 6, dd = cl & 63;
        const float bv_ = bias[wc * 64 + nf * 16 + l15];
        #pragma unroll
        for (int mf = 0; mf < 4; ++mf)
            #pragma unroll
            for (int r = 0; r < 4; ++r) {
                const int m = m0 + wr * 64 + mf * 16 + lg * 4 + r;
                const int bb_ = m >> 11, ss = m & (SS_ - 1);
                dst[(((size_t)bb_ * nh + hh) * SS_ + ss) * HD + dd] = f2bf(acc[mf][nf][r] + bv_);
            }
    }
}

// ---------------------------------------------------------------------------
// K2: flash attention, 32x32x16 bf16 MFMA, swapped QK^T, in-register P,
// static-max softmax. Round-15 change: TWO kv-tiles per barrier (double-
// buffered tile-pairs, 16 barriers instead of 32; deeper load in-flight).
// ---------------------------------------------------------------------------
__global__ __launch_bounds__(512, 4) void attn_kernel(
    const u16* __restrict__ q, const u16* __restrict__ k,
    const u16* __restrict__ v, u16* __restrict__ o)
{
    union SMem {
        struct { u16 Ks[2][2][KT][LDK]; u16 Vt[2][2][HD][LDV]; } s;   // 71680 B
        u16 Ot[QT][LDO];                                              // 33792 B
    };
    __shared__ SMem sm;

    const int tid = threadIdx.x;
    const int w   = tid >> 6;        // 0..7
    const int l   = tid & 63;
    const int l31 = l & 31;
    const int hi  = l >> 5;
    const int qt  = blockIdx.x;      // 0..7
    const int h   = blockIdx.y;
    const int b   = blockIdx.z;
    const int hk  = h >> 2;

    const u16* qb = q + (((size_t)b * NH  + h ) * SS_ + qt * QT) * HD;
    const u16* kp = k + (((size_t)b * NKV + hk) * SS_) * HD;
    const u16* vp = v + (((size_t)b * NKV + hk) * SS_) * HD;

    // Q B-frags: col = qrow = w*32+l31, k = d = kc*16 + hi*8 + j
    bf16x8 qf[4];
    #pragma unroll
    for (int kc = 0; kc < 4; ++kc)
        qf[kc] = *(const bf16x8*)&qb[(size_t)(w * 32 + l31) * HD + kc * 16 + hi * 8];

    f32x16 oaccT[2] = {};   // col=qrow=l31; row=d = db*32 + (r&3)+8*(r>>2)+4*hi
    float d0s = 0.f, d1s = 0.f, d2s = 0.f, d3s = 0.f;   // denom partials
    const float C = 0.1803368801f;   // 0.125 * log2(e)

    // staging indices for 512 threads:
    const int krow = tid >> 3, kcol = (tid & 7) << 3;        // K: 1 bf16x8 each
    const int vk0  = (tid & 31) << 1, vd0 = (tid >> 5) << 2; // V: 2 kv x 4 d

    const int NT = SS_ / KT;   // 32

    // ---- prologue: stage tiles 0,1 into pair 0
    #pragma unroll
    for (int s = 0; s < 2; ++s) {
        bf16x8 kr0 = *(const bf16x8*)&kp[(size_t)(s * KT + krow) * HD + kcol];
        uint2 vv[2];
        #pragma unroll
        for (int i = 0; i < 2; ++i)
            vv[i] = *(const uint2*)&vp[(size_t)(s * KT + vk0 + i) * HD + vd0];
        *(bf16x8*)&sm.s.Ks[0][s][krow][kcol] = kr0;
        #pragma unroll
        for (int j = 0; j < 4; ++j) {
            ushort2 tv;
            tv.x = ((const u16*)&vv[0])[j];
            tv.y = ((const u16*)&vv[1])[j];
            *(ushort2*)&sm.s.Vt[0][s][vd0 + j][vk0] = tv;
        }
    }
    __syncthreads();

    int p = 0;
    for (int i = 0; i < NT / 2; ++i) {
        // ---- issue loads for the next tile-pair (clamped on last iter)
        bf16x8 nk[2];
        uint2  nv[2][2];
        #pragma unroll
        for (int s = 0; s < 2; ++s) {
            const int t  = 2 * i + s;
            const int tn = (t + 2 < NT) ? (t + 2) : t;
            nk[s] = *(const bf16x8*)&kp[(size_t)(tn * KT + krow) * HD + kcol];
            #pragma unroll
            for (int j = 0; j < 2; ++j)
                nv[s][j] = *(const uint2*)&vp[(size_t)(tn * KT + vk0 + j) * HD + vd0];
        }

        // ---- compute both sub-tiles of pair p
        #pragma unroll
        for (int s = 0; s < 2; ++s) {
            // S^T = K · Q^T
            f32x16 st[2] = {};
            __builtin_amdgcn_s_setprio(1);
            #pragma unroll
            for (int kb = 0; kb < 2; ++kb)
                #pragma unroll
                for (int kc = 0; kc < 4; ++kc) {
                    bf16x8 kf = *(const bf16x8*)&sm.s.Ks[p][s][kb * 32 + l31][kc * 16 + hi * 8];
                    st[kb] = __builtin_amdgcn_mfma_f32_32x32x16_bf16(kf, qf[kc], st[kb], 0, 0, 0);
                }
            __builtin_amdgcn_s_setprio(0);

            // static-max softmax: P = 2^(S * 0.125*log2e); accumulate denom
            #pragma unroll
            for (int kb = 0; kb < 2; ++kb)
                #pragma unroll
                for (int r = 0; r < 16; r += 4) {
                    const float p0 = exp2f(st[kb][r + 0] * C);
                    const float p1 = exp2f(st[kb][r + 1] * C);
                    const float p2 = exp2f(st[kb][r + 2] * C);
                    const float p3 = exp2f(st[kb][r + 3] * C);
                    st[kb][r + 0] = p0; st[kb][r + 1] = p1;
                    st[kb][r + 2] = p2; st[kb][r + 3] = p3;
                    d0s += p0; d1s += p1; d2s += p2; d3s += p3;
                }

            // O^T += V^T · P^T, pack interleaved per kc (1-instr RTZ pack)
            #pragma unroll
            for (int kc = 0; kc < 4; ++kc) {
                const int kb = kc >> 1, c4 = (kc & 1) * 4;
                const unsigned int a0 = pack_rtz(st[kb][2 * (c4 + 0)], st[kb][2 * (c4 + 0) + 1]);
                const unsigned int a1 = pack_rtz(st[kb][2 * (c4 + 1)], st[kb][2 * (c4 + 1) + 1]);
                const unsigned int a2 = pack_rtz(st[kb][2 * (c4 + 2)], st[kb][2 * (c4 + 2) + 1]);
                const unsigned int a3 = pack_rtz(st[kb][2 * (c4 + 3)], st[kb][2 * (c4 + 3) + 1]);
                const unsigned int b0 = (unsigned int)__shfl_xor((int)a0, 32);
                const unsigned int b1 = (unsigned int)__shfl_xor((int)a1, 32);
                const unsigned int b2 = (unsigned int)__shfl_xor((int)a2, 32);
                const unsigned int b3 = (unsigned int)__shfl_xor((int)a3, 32);
                uint4 pbu;
                pbu.x = hi ? b2 : a0;
                pbu.y = hi ? b3 : a1;
                pbu.z = hi ? a2 : b0;
                pbu.w = hi ? a3 : b1;
                bf16x8 pb = *(bf16x8*)&pbu;
                __builtin_amdgcn_s_setprio(1);
                #pragma unroll
                for (int db = 0; db < 2; ++db) {
                    bf16x8 vf = *(const bf16x8*)&sm.s.Vt[p][s][db * 32 + l31][kc * 16 + hi * 8];
                    oaccT[db] = __builtin_amdgcn_mfma_f32_32x32x16_bf16(vf, pb, oaccT[db], 0, 0, 0);
                }
                __builtin_amdgcn_s_setprio(0);
            }
        }

        // ---- stage next pair into p^1
        #pragma unroll
        for (int s = 0; s < 2; ++s) {
            *(bf16x8*)&sm.s.Ks[p ^ 1][s][krow][kcol] = nk[s];
            #pragma unroll
            for (int j = 0; j < 4; ++j) {
                ushort2 tv;
                tv.x = ((const u16*)&nv[s][0])[j];
                tv.y = ((const u16*)&nv[s][1])[j];
                *(ushort2*)&sm.s.Vt[p ^ 1][s][vd0 + j][vk0] = tv;
            }
        }
        __syncthreads();   // ONE barrier per 2 kv-tiles
        p ^= 1;
    }

    // ---- final denominator (single cross-lane reduce)
    float l_i = (d0s + d1s) + (d2s + d3s);
    l_i += __shfl_xor(l_i, 32);
    const float inv = 1.0f / l_i;

    // ---- epilogue: normalize, transpose via LDS, coalesced bf16 stores
    #pragma unroll
    for (int db = 0; db < 2; ++db)
        #pragma unroll
        for (int pp = 0; pp < 8; ++pp) {
            const int d0 = db * 32 + 2 * (pp & 1) + 4 * hi + 8 * (pp >> 1);
            unsigned int r_ = pack_bf2(oaccT[db][2 * pp] * inv, oaccT[db][2 * pp + 1] * inv);
            *(unsigned int*)&sm.Ot[w * 32 + l31][d0] = r_;
        }
    __syncthreads();
    {
        const int row = tid >> 1, half = tid & 1;   // 512 threads, 256 rows
        u16* go = o + ((size_t)b * SS_ + qt * QT + row) * HID + h * HD + half * 32;
        #pragma unroll
        for (int u = 0; u < 2; ++u) {
            uint4 t0 = *(uint4*)&sm.Ot[row][half * 32 + u * 16];
            *(uint4*)&go[u * 16] = t0;
            uint4 t1 = *(uint4*)&sm.Ot[row][half * 32 + u * 16 + 8];
            *(uint4*)&go[u * 16 + 8] = t1;
        }
    }
}

// ---------------------------------------------------------------------------
// K3: output projection, bf16 MFMA (round-11 form).
// ---------------------------------------------------------------------------
__global__ __launch_bounds__(256) void oproj_kernel(
    const u16* __restrict__ Ab, const u16* __restrict__ To,
    const float* __restrict__ bo, float* __restrict__ out)
{
    __shared__ u16 Al[128][36];
    __shared__ u16 Bl[128][36];
    const int tid = threadIdx.x;
    const int w = tid >> 6, l15 = tid & 15, lg = (tid & 63) >> 4;
    const int wr = w >> 1, wc = w & 1;
    const int m0 = blockIdx.x * 128;
    const int n0 = blockIdx.y * 128;

    const int sm = tid >> 2;
    const int sk = (tid & 3) << 3;

    f32x4 acc[4][4] = {};
    for (int k0 = 0; k0 < HID; k0 += 32) {
        bf16x8 a0 = *(const bf16x8*)&Ab[(size_t)(m0 + sm) * HID + k0 + sk];
        bf16x8 a1 = *(const bf16x8*)&Ab[(size_t)(m0 + 64 + sm) * HID + k0 + sk];
        bf16x8 b0 = *(const bf16x8*)&To[(size_t)(n0 + sm) * HID + k0 + sk];
        bf16x8 b1 = *(const bf16x8*)&To[(size_t)(n0 + 64 + sm) * HID + k0 + sk];
        __syncthreads();
        *(bf16x8*)&Al[sm][sk]      = a0;
        *(bf16x8*)&Al[64 + sm][sk] = a1;
        *(bf16x8*)&Bl[sm][sk]      = b0;
        *(bf16x8*)&Bl[64 + sm][sk] = b1;
        __syncthreads();
        bf16x8 af[4], bfr[4];
        #pragma unroll
        for (int i = 0; i < 4; ++i) {
            af[i]  = *(const bf16x8*)&Al[wr * 64 + i * 16 + l15][lg * 8];
            bfr[i] = *(const bf16x8*)&Bl[wc * 64 + i * 16 + l15][lg * 8];
        }
        #pragma unroll
        for (int mf = 0; mf < 4; ++mf)
            #pragma unroll
            for (int nf = 0; nf < 4; ++nf)
                acc[mf][nf] = __builtin_amdgcn_mfma_f32_16x16x32_bf16(af[mf], bfr[nf], acc[mf][nf], 0, 0, 0);
    }

    #pragma unroll
    for (int nf = 0; nf < 4; ++nf) {
        const int col = n0 + wc * 64 + nf * 16 + l15;
        const float bv_ = bo[col];
        #pragma unroll
        for (int mf = 0; mf < 4; ++mf)
            #pragma unroll
            for (int r = 0; r < 4; ++r) {
                const int m = m0 + wr * 64 + mf * 16 + lg * 4 + r;
                out[(size_t)m * HID + col] = acc[mf][nf][r] + bv_;
            }
    }
}

// ---------------------------------------------------------------------------
extern "C" void kernel_launch(void* const* d_in, const int* in_sizes, int n_in,
                              void* d_out, int out_size, void* d_ws, size_t ws_size,
                              hipStream_t stream) {
    int iX = 0, iWq = 1, ibq = 2, iWk = 3, ibk = 4, iWv = 5, ibv = 6, iWo = 7, ibo = 8;
    if (n_in == 9 && in_sizes[1] == 1048576) {   // alphabetical-order hedge
        iWk = 1; iWo = 2; iWq = 3; iWv = 4; ibk = 5; ibo = 6; ibq = 7; ibv = 8;
    }
    const float* X  = (const float*)d_in[iX];
    const float* Wq = (const float*)d_in[iWq];
    const float* bq = (const float*)d_in[ibq];
    const float* Wk = (const float*)d_in[iWk];
    const float* bk = (const float*)d_in[ibk];
    const float* Wv = (const float*)d_in[iWv];
    const float* bv = (const float*)d_in[ibv];
    const float* Wo = (const float*)d_in[iWo];
    const float* bo = (const float*)d_in[ibo];
    float* out = (float*)d_out;

    u16* Xb  = (u16*)d_ws;                                  // [4096][2048]
    u16* Tq  = Xb  + (size_t)MM * HID;                      // [2048][2048]
    u16* Tk  = Tq  + (size_t)HID * HID;                     // [512][2048]
    u16* Tv  = Tk  + (size_t)512 * HID;                     // [512][2048]
    u16* To  = Tv  + (size_t)512 * HID;                     // [2048][2048]
    u16* qws = To  + (size_t)HID * HID;                     // [2,32,2048,64]
    u16* kws = qws + (size_t)BB * NH  * SS_ * HD;           // [2,8,2048,64]
    u16* vws = kws + (size_t)BB * NKV * SS_ * HD;           // [2,8,2048,64]
    u16* ows = vws + (size_t)BB * NKV * SS_ * HD;           // [4096][2048]

    cvt_kernel<<<dim3((MM * HID / 4 + 255) / 256), 256, 0, stream>>>(X, Xb, MM * HID / 4);
    tw_kernel<<<dim3(32, 80), 256, 0, stream>>>(Wq, Wk, Wv, Wo, Tq, Tk, Tv, To);
    proj_kernel<<<dim3(32, 24), 256, 0, stream>>>(Xb, Tq, Tk, Tv, bq, bk, bv, qws, kws, vws);
    attn_kernel<<<dim3(SS_ / QT, 32, 2), 512, 0, stream>>>(qws, kws, vws, ows);
    oproj_kernel<<<dim3(32, 16), 256, 0, stream>>>(ows, To, bo, out);
}

// Round 16
// 323.982 us; speedup vs baseline: 1.2116x; 1.2116x over previous
//
#include <hip/hip_runtime.h>
#include <hip/hip_bf16.h>

#define HID 2048
#define NH 32
#define NKV 8
#define HD 64
#define BB 2
#define SS_ 2048
#define MM (BB * SS_)     // 4096 rows

#define QT 256            // q rows per attn block (8 waves x 32)
#define KT 64             // kv rows per tile
#define LDK 72            // padded stride (u16) for Ks
#define LDV 68            // padded stride (u16) for Vt
#define LDO 66            // padded stride (u16) for Ot

typedef unsigned short u16;
typedef __attribute__((ext_vector_type(8)))  short bf16x8;
typedef __attribute__((ext_vector_type(4)))  float f32x4;
typedef __attribute__((ext_vector_type(16))) float f32x16;
typedef __attribute__((ext_vector_type(2)))  unsigned int u32x2;

__device__ __forceinline__ u16 f2bf(float f) {
    union { float f; unsigned int i; } v; v.f = f;
    unsigned int lsb = (v.i >> 16) & 1u;
    v.i += 0x7fffu + lsb;               // round-to-nearest-even
    return (u16)(v.i >> 16);
}
// RTN pack (epilogue only): LOW u16 = lo
__device__ __forceinline__ unsigned int pack_bf2(float lo, float hi) {
    return ((unsigned int)f2bf(hi) << 16) | (unsigned int)f2bf(lo);
}
// 1-instr RTZ pack via v_perm_b32 byte-select: D = {hi[31:16], lo[31:16]}
__device__ __forceinline__ unsigned int pack_rtz(float lo, float hi) {
    return __builtin_amdgcn_perm(__float_as_uint(hi), __float_as_uint(lo), 0x07060302u);
}

// ---------------------------------------------------------------------------
// K0a: straight fp32 -> bf16 convert (X)
// ---------------------------------------------------------------------------
__global__ __launch_bounds__(256) void cvt_kernel(
    const float* __restrict__ in, u16* __restrict__ out, int n4)
{
    const int i = blockIdx.x * 256 + threadIdx.x;
    if (i < n4) {
        float4 f = ((const float4*)in)[i];
        ushort4 r;
        r.x = f2bf(f.x); r.y = f2bf(f.y); r.z = f2bf(f.z); r.w = f2bf(f.w);
        ((ushort4*)out)[i] = r;
    }
}

// ---------------------------------------------------------------------------
// K0b: transpose-convert weights: fp32 [K][N] -> bf16 [N][K].
// ---------------------------------------------------------------------------
__global__ __launch_bounds__(256) void tw_kernel(
    const float* __restrict__ Wq, const float* __restrict__ Wk,
    const float* __restrict__ Wv, const float* __restrict__ Wo,
    u16* __restrict__ Tq, u16* __restrict__ Tk,
    u16* __restrict__ Tv, u16* __restrict__ To)
{
    __shared__ float tile[64][65];
    const int by = blockIdx.y;
    const float* W; u16* T; int N, n0;
    if (by < 32)      { W = Wq; T = Tq; N = 2048; n0 = by * 64; }
    else if (by < 40) { W = Wk; T = Tk; N = 512;  n0 = (by - 32) * 64; }
    else if (by < 48) { W = Wv; T = Tv; N = 512;  n0 = (by - 40) * 64; }
    else              { W = Wo; T = To; N = 2048; n0 = (by - 48) * 64; }
    const int k0 = blockIdx.x * 64;
    const int r  = threadIdx.x >> 2;
    const int c0 = (threadIdx.x & 3) << 4;
    #pragma unroll
    for (int u = 0; u < 4; ++u) {
        float4 f = *(const float4*)&W[(size_t)(k0 + r) * N + n0 + c0 + u * 4];
        tile[r][c0 + u * 4 + 0] = f.x; tile[r][c0 + u * 4 + 1] = f.y;
        tile[r][c0 + u * 4 + 2] = f.z; tile[r][c0 + u * 4 + 3] = f.w;
    }
    __syncthreads();
    #pragma unroll
    for (int u = 0; u < 4; ++u) {
        ushort4 o;
        o.x = f2bf(tile[c0 + u * 4 + 0][r]);
        o.y = f2bf(tile[c0 + u * 4 + 1][r]);
        o.z = f2bf(tile[c0 + u * 4 + 2][r]);
        o.w = f2bf(tile[c0 + u * 4 + 3][r]);
        *(ushort4*)&T[(size_t)(n0 + r) * HID + k0 + c0 + u * 4] = o;
    }
}

// ---------------------------------------------------------------------------
// K1: QKV projection, bf16 MFMA (16x16x32), 128x128x32 tile (round-11 form).
// ---------------------------------------------------------------------------
__global__ __launch_bounds__(256) void proj_kernel(
    const u16* __restrict__ Xb,
    const u16* __restrict__ Tq, const u16* __restrict__ Tk, const u16* __restrict__ Tv,
    const float* __restrict__ bq, const float* __restrict__ bk, const float* __restrict__ bv,
    u16* __restrict__ qo, u16* __restrict__ ko, u16* __restrict__ vo)
{
    __shared__ u16 Al[128][36];
    __shared__ u16 Bl[128][36];
    const int tid = threadIdx.x;
    const int w = tid >> 6, l15 = tid & 15, lg = (tid & 63) >> 4;
    const int wr = w >> 1, wc = w & 1;
    const int m0 = blockIdx.x * 128;
    const int n0 = blockIdx.y * 128;

    const u16* Bt; const float* bias; u16* dst; int nh, nb;
    if (n0 < 2048)      { Bt = Tq + (size_t)n0 * HID;          bias = bq + n0;          dst = qo; nh = NH;  nb = n0; }
    else if (n0 < 2560) { Bt = Tk + (size_t)(n0 - 2048) * HID; bias = bk + (n0 - 2048); dst = ko; nh = NKV; nb = n0 - 2048; }
    else                { Bt = Tv + (size_t)(n0 - 2560) * HID; bias = bv + (n0 - 2560); dst = vo; nh = NKV; nb = n0 - 2560; }

    const int sm = tid >> 2;
    const int sk = (tid & 3) << 3;

    f32x4 acc[4][4] = {};
    for (int k0 = 0; k0 < HID; k0 += 32) {
        bf16x8 a0 = *(const bf16x8*)&Xb[(size_t)(m0 + sm) * HID + k0 + sk];
        bf16x8 a1 = *(const bf16x8*)&Xb[(size_t)(m0 + 64 + sm) * HID + k0 + sk];
        bf16x8 b0 = *(const bf16x8*)&Bt[(size_t)sm * HID + k0 + sk];
        bf16x8 b1 = *(const bf16x8*)&Bt[(size_t)(64 + sm) * HID + k0 + sk];
        __syncthreads();
        *(bf16x8*)&Al[sm][sk]      = a0;
        *(bf16x8*)&Al[64 + sm][sk] = a1;
        *(bf16x8*)&Bl[sm][sk]      = b0;
        *(bf16x8*)&Bl[64 + sm][sk] = b1;
        __syncthreads();
        bf16x8 af[4], bfr[4];
        #pragma unroll
        for (int i = 0; i < 4; ++i) {
            af[i]  = *(const bf16x8*)&Al[wr * 64 + i * 16 + l15][lg * 8];
            bfr[i] = *(const bf16x8*)&Bl[wc * 64 + i * 16 + l15][lg * 8];
        }
        #pragma unroll
        for (int mf = 0; mf < 4; ++mf)
            #pragma unroll
            for (int nf = 0; nf < 4; ++nf)
                acc[mf][nf] = __builtin_amdgcn_mfma_f32_16x16x32_bf16(af[mf], bfr[nf], acc[mf][nf], 0, 0, 0);
    }

    #pragma unroll
    for (int nf = 0; nf < 4; ++nf) {
        const int cl = nb + wc * 64 + nf * 16 + l15;
        const int hh = cl >> 6, dd = cl & 63;
        const float bv_ = bias[wc * 64 + nf * 16 + l15];
        #pragma unroll
        for (int mf = 0; mf < 4; ++mf)
            #pragma unroll
            for (int r = 0; r < 4; ++r) {
                const int m = m0 + wr * 64 + mf * 16 + lg * 4 + r;
                const int bb_ = m >> 11, ss = m & (SS_ - 1);
                dst[(((size_t)bb_ * nh + hh) * SS_ + ss) * HD + dd] = f2bf(acc[mf][nf][r] + bv_);
            }
    }
}

// ---------------------------------------------------------------------------
// K2: flash attention, 32x32x16 bf16 MFMA, swapped QK^T, in-register P,
// static-max softmax, double-buffered, one barrier/tile (round-14 body).
// Round-16 change: P-redistribution via v_permlane32_swap (2 ops/kc) instead
// of 4x ds_bpermute(shfl_xor) + 4x cndmask.
// ---------------------------------------------------------------------------
__global__ __launch_bounds__(512, 4) void attn_kernel(
    const u16* __restrict__ q, const u16* __restrict__ k,
    const u16* __restrict__ v, u16* __restrict__ o)
{
    union SMem {
        struct { u16 Ks[2][KT][LDK]; u16 Vt[2][HD][LDV]; } s;   // 35840 B
        u16 Ot[QT][LDO];                                        // 33792 B
    };
    __shared__ SMem sm;

    const int tid = threadIdx.x;
    const int w   = tid >> 6;        // 0..7
    const int l   = tid & 63;
    const int l31 = l & 31;
    const int hi  = l >> 5;
    const int qt  = blockIdx.x;      // 0..7
    const int h   = blockIdx.y;
    const int b   = blockIdx.z;
    const int hk  = h >> 2;

    const u16* qb = q + (((size_t)b * NH  + h ) * SS_ + qt * QT) * HD;
    const u16* kp = k + (((size_t)b * NKV + hk) * SS_) * HD;
    const u16* vp = v + (((size_t)b * NKV + hk) * SS_) * HD;

    // Q B-frags: col = qrow = w*32+l31, k = d = kc*16 + hi*8 + j
    bf16x8 qf[4];
    #pragma unroll
    for (int kc = 0; kc < 4; ++kc)
        qf[kc] = *(const bf16x8*)&qb[(size_t)(w * 32 + l31) * HD + kc * 16 + hi * 8];

    f32x16 oaccT[2] = {};   // col=qrow=l31; row=d = db*32 + (r&3)+8*(r>>2)+4*hi
    float d0s = 0.f, d1s = 0.f, d2s = 0.f, d3s = 0.f;   // denom partials
    const float C = 0.1803368801f;   // 0.125 * log2(e)

    // staging indices for 512 threads:
    const int krow = tid >> 3, kcol = (tid & 7) << 3;        // K: 1 bf16x8 each
    const int vk0  = (tid & 31) << 1, vd0 = (tid >> 5) << 2; // V: 2 kv x 4 d

    const int NT = SS_ / KT;   // 32

    // ---- prologue: stage tile 0 into buf 0
    {
        bf16x8 kr0 = *(const bf16x8*)&kp[(size_t)krow * HD + kcol];
        uint2 vv[2];
        #pragma unroll
        for (int i = 0; i < 2; ++i)
            vv[i] = *(const uint2*)&vp[(size_t)(vk0 + i) * HD + vd0];
        *(bf16x8*)&sm.s.Ks[0][krow][kcol] = kr0;
        #pragma unroll
        for (int j = 0; j < 4; ++j) {
            ushort2 tv;
            tv.x = ((const u16*)&vv[0])[j];
            tv.y = ((const u16*)&vv[1])[j];
            *(ushort2*)&sm.s.Vt[0][vd0 + j][vk0] = tv;
        }
    }
    __syncthreads();

    int p = 0;
    for (int t = 0; t < NT; ++t) {
        // ---- issue next-tile loads (clamped on last iter)
        const int tn = (t + 1 < NT) ? (t + 1) : (NT - 1);
        bf16x8 nk0 = *(const bf16x8*)&kp[(size_t)(tn * KT + krow) * HD + kcol];
        uint2 nv[2];
        #pragma unroll
        for (int i = 0; i < 2; ++i)
            nv[i] = *(const uint2*)&vp[(size_t)(tn * KT + vk0 + i) * HD + vd0];

        // ---- S^T = K · Q^T   (from buf p)
        f32x16 st[2] = {};
        __builtin_amdgcn_s_setprio(1);
        #pragma unroll
        for (int kb = 0; kb < 2; ++kb)
            #pragma unroll
            for (int kc = 0; kc < 4; ++kc) {
                bf16x8 kf = *(const bf16x8*)&sm.s.Ks[p][kb * 32 + l31][kc * 16 + hi * 8];
                st[kb] = __builtin_amdgcn_mfma_f32_32x32x16_bf16(kf, qf[kc], st[kb], 0, 0, 0);
            }
        __builtin_amdgcn_s_setprio(0);

        // ---- static-max softmax: P = 2^(S * 0.125*log2e); accumulate denom
        #pragma unroll
        for (int kb = 0; kb < 2; ++kb)
            #pragma unroll
            for (int r = 0; r < 16; r += 4) {
                const float p0 = exp2f(st[kb][r + 0] * C);
                const float p1 = exp2f(st[kb][r + 1] * C);
                const float p2 = exp2f(st[kb][r + 2] * C);
                const float p3 = exp2f(st[kb][r + 3] * C);
                st[kb][r + 0] = p0; st[kb][r + 1] = p1;
                st[kb][r + 2] = p2; st[kb][r + 3] = p3;
                d0s += p0; d1s += p1; d2s += p2; d3s += p3;
            }

        // ---- O^T += V^T · P^T; P halves exchanged via v_permlane32_swap:
        // r=swap(a0,a2): r.x[i<32]=a0, r.x[i>=32]=a2[i-32]  (== old pbu.x)
        //                r.y[i<32]=a0[i+32], r.y[i>=32]=a2  (== old pbu.z)
        #pragma unroll
        for (int kc = 0; kc < 4; ++kc) {
            const int kb = kc >> 1, c4 = (kc & 1) * 4;
            const unsigned int a0 = pack_rtz(st[kb][2 * (c4 + 0)], st[kb][2 * (c4 + 0) + 1]);
            const unsigned int a1 = pack_rtz(st[kb][2 * (c4 + 1)], st[kb][2 * (c4 + 1) + 1]);
            const unsigned int a2 = pack_rtz(st[kb][2 * (c4 + 2)], st[kb][2 * (c4 + 2) + 1]);
            const unsigned int a3 = pack_rtz(st[kb][2 * (c4 + 3)], st[kb][2 * (c4 + 3) + 1]);
            u32x2 r0 = __builtin_amdgcn_permlane32_swap(a0, a2, false, false);
            u32x2 r1 = __builtin_amdgcn_permlane32_swap(a1, a3, false, false);
            uint4 pbu;
            pbu.x = r0.x;
            pbu.y = r1.x;
            pbu.z = r0.y;
            pbu.w = r1.y;
            bf16x8 pb = *(bf16x8*)&pbu;
            __builtin_amdgcn_s_setprio(1);
            #pragma unroll
            for (int db = 0; db < 2; ++db) {
                bf16x8 vf = *(const bf16x8*)&sm.s.Vt[p][db * 32 + l31][kc * 16 + hi * 8];
                oaccT[db] = __builtin_amdgcn_mfma_f32_32x32x16_bf16(vf, pb, oaccT[db], 0, 0, 0);
            }
            __builtin_amdgcn_s_setprio(0);
        }

        // ---- stage tile t+1 into buf p^1
        if (t + 1 < NT) {
            *(bf16x8*)&sm.s.Ks[p ^ 1][krow][kcol] = nk0;
            #pragma unroll
            for (int j = 0; j < 4; ++j) {
                ushort2 tv;
                tv.x = ((const u16*)&nv[0])[j];
                tv.y = ((const u16*)&nv[1])[j];
                *(ushort2*)&sm.s.Vt[p ^ 1][vd0 + j][vk0] = tv;
            }
        }
        __syncthreads();
        p ^= 1;
    }

    // ---- final denominator (single cross-lane reduce)
    float l_i = (d0s + d1s) + (d2s + d3s);
    l_i += __shfl_xor(l_i, 32);
    const float inv = 1.0f / l_i;

    // ---- epilogue: normalize, transpose via LDS, coalesced bf16 stores
    #pragma unroll
    for (int db = 0; db < 2; ++db)
        #pragma unroll
        for (int pp = 0; pp < 8; ++pp) {
            const int d0 = db * 32 + 2 * (pp & 1) + 4 * hi + 8 * (pp >> 1);
            unsigned int r_ = pack_bf2(oaccT[db][2 * pp] * inv, oaccT[db][2 * pp + 1] * inv);
            *(unsigned int*)&sm.Ot[w * 32 + l31][d0] = r_;
        }
    __syncthreads();
    {
        const int row = tid >> 1, half = tid & 1;   // 512 threads, 256 rows
        u16* go = o + ((size_t)b * SS_ + qt * QT + row) * HID + h * HD + half * 32;
        #pragma unroll
        for (int u = 0; u < 2; ++u) {
            uint4 t0 = *(uint4*)&sm.Ot[row][half * 32 + u * 16];
            *(uint4*)&go[u * 16] = t0;
            uint4 t1 = *(uint4*)&sm.Ot[row][half * 32 + u * 16 + 8];
            *(uint4*)&go[u * 16 + 8] = t1;
        }
    }
}

// ---------------------------------------------------------------------------
// K3: output projection, bf16 MFMA (round-11 form).
// ---------------------------------------------------------------------------
__global__ __launch_bounds__(256) void oproj_kernel(
    const u16* __restrict__ Ab, const u16* __restrict__ To,
    const float* __restrict__ bo, float* __restrict__ out)
{
    __shared__ u16 Al[128][36];
    __shared__ u16 Bl[128][36];
    const int tid = threadIdx.x;
    const int w = tid >> 6, l15 = tid & 15, lg = (tid & 63) >> 4;
    const int wr = w >> 1, wc = w & 1;
    const int m0 = blockIdx.x * 128;
    const int n0 = blockIdx.y * 128;

    const int sm = tid >> 2;
    const int sk = (tid & 3) << 3;

    f32x4 acc[4][4] = {};
    for (int k0 = 0; k0 < HID; k0 += 32) {
        bf16x8 a0 = *(const bf16x8*)&Ab[(size_t)(m0 + sm) * HID + k0 + sk];
        bf16x8 a1 = *(const bf16x8*)&Ab[(size_t)(m0 + 64 + sm) * HID + k0 + sk];
        bf16x8 b0 = *(const bf16x8*)&To[(size_t)(n0 + sm) * HID + k0 + sk];
        bf16x8 b1 = *(const bf16x8*)&To[(size_t)(n0 + 64 + sm) * HID + k0 + sk];
        __syncthreads();
        *(bf16x8*)&Al[sm][sk]      = a0;
        *(bf16x8*)&Al[64 + sm][sk] = a1;
        *(bf16x8*)&Bl[sm][sk]      = b0;
        *(bf16x8*)&Bl[64 + sm][sk] = b1;
        __syncthreads();
        bf16x8 af[4], bfr[4];
        #pragma unroll
        for (int i = 0; i < 4; ++i) {
            af[i]  = *(const bf16x8*)&Al[wr * 64 + i * 16 + l15][lg * 8];
            bfr[i] = *(const bf16x8*)&Bl[wc * 64 + i * 16 + l15][lg * 8];
        }
        #pragma unroll
        for (int mf = 0; mf < 4; ++mf)
            #pragma unroll
            for (int nf = 0; nf < 4; ++nf)
                acc[mf][nf] = __builtin_amdgcn_mfma_f32_16x16x32_bf16(af[mf], bfr[nf], acc[mf][nf], 0, 0, 0);
    }

    #pragma unroll
    for (int nf = 0; nf < 4; ++nf) {
        const int col = n0 + wc * 64 + nf * 16 + l15;
        const float bv_ = bo[col];
        #pragma unroll
        for (int mf = 0; mf < 4; ++mf)
            #pragma unroll
            for (int r = 0; r < 4; ++r) {
                const int m = m0 + wr * 64 + mf * 16 + lg * 4 + r;
                out[(size_t)m * HID + col] = acc[mf][nf][r] + bv_;
            }
    }
}

// ---------------------------------------------------------------------------
extern "C" void kernel_launch(void* const* d_in, const int* in_sizes, int n_in,
                              void* d_out, int out_size, void* d_ws, size_t ws_size,
                              hipStream_t stream) {
    int iX = 0, iWq = 1, ibq = 2, iWk = 3, ibk = 4, iWv = 5, ibv = 6, iWo = 7, ibo = 8;
    if (n_in == 9 && in_sizes[1] == 1048576) {   // alphabetical-order hedge
        iWk = 1; iWo = 2; iWq = 3; iWv = 4; ibk = 5; ibo = 6; ibq = 7; ibv = 8;
    }
    const float* X  = (const float*)d_in[iX];
    const float* Wq = (const float*)d_in[iWq];
    const float* bq = (const float*)d_in[ibq];
    const float* Wk = (const float*)d_in[iWk];
    const float* bk = (const float*)d_in[ibk];
    const float* Wv = (const float*)d_in[iWv];
    const float* bv = (const float*)d_in[ibv];
    const float* Wo = (const float*)d_in[iWo];
    const float* bo = (const float*)d_in[ibo];
    float* out = (float*)d_out;

    u16* Xb  = (u16*)d_ws;                                  // [4096][2048]
    u16* Tq  = Xb  + (size_t)MM * HID;                      // [2048][2048]
    u16* Tk  = Tq  + (size_t)HID * HID;                     // [512][2048]
    u16* Tv  = Tk  + (size_t)512 * HID;                     // [512][2048]
    u16* To  = Tv  + (size_t)512 * HID;                     // [2048][2048]
    u16* qws = To  + (size_t)HID * HID;                     // [2,32,2048,64]
    u16* kws = qws + (size_t)BB * NH  * SS_ * HD;           // [2,8,2048,64]
    u16* vws = kws + (size_t)BB * NKV * SS_ * HD;           // [2,8,2048,64]
    u16* ows = vws + (size_t)BB * NKV * SS_ * HD;           // [4096][2048]

    cvt_kernel<<<dim3((MM * HID / 4 + 255) / 256), 256, 0, stream>>>(X, Xb, MM * HID / 4);
    tw_kernel<<<dim3(32, 80), 256, 0, stream>>>(Wq, Wk, Wv, Wo, Tq, Tk, Tv, To);
    proj_kernel<<<dim3(32, 24), 256, 0, stream>>>(Xb, Tq, Tk, Tv, bq, bk, bv, qws, kws, vws);
    attn_kernel<<<dim3(SS_ / QT, 32, 2), 512, 0, stream>>>(qws, kws, vws, ows);
    oproj_kernel<<<dim3(32, 16), 256, 0, stream>>>(ows, To, bo, out);
}

// Round 17
// 305.680 us; speedup vs baseline: 1.2842x; 1.0599x over previous
//
#include <hip/hip_runtime.h>
#include <hip/hip_bf16.h>

#define HID 2048
#define NH 32
#define NKV 8
#define HD 64
#define BB 2
#define SS_ 2048
#define MM (BB * SS_)     // 4096 rows

#define QT 256            // q rows per attn block (8 waves x 32)
#define KT 64             // kv rows per tile
#define LDK 72            // padded stride (u16) for Ks
#define LDV 68            // padded stride (u16) for Vt
#define LDO 66            // padded stride (u16) for Ot

typedef unsigned short u16;
typedef __attribute__((ext_vector_type(8)))  short bf16x8;
typedef __attribute__((ext_vector_type(4)))  float f32x4;
typedef __attribute__((ext_vector_type(16))) float f32x16;
typedef __attribute__((ext_vector_type(2)))  unsigned int u32x2;

__device__ __forceinline__ u16 f2bf(float f) {
    union { float f; unsigned int i; } v; v.f = f;
    unsigned int lsb = (v.i >> 16) & 1u;
    v.i += 0x7fffu + lsb;               // round-to-nearest-even
    return (u16)(v.i >> 16);
}
// RTN pack (epilogue only): LOW u16 = lo
__device__ __forceinline__ unsigned int pack_bf2(float lo, float hi) {
    return ((unsigned int)f2bf(hi) << 16) | (unsigned int)f2bf(lo);
}
// 1-instr RTZ pack via v_perm_b32 byte-select: D = {hi[31:16], lo[31:16]}
__device__ __forceinline__ unsigned int pack_rtz(float lo, float hi) {
    return __builtin_amdgcn_perm(__float_as_uint(hi), __float_as_uint(lo), 0x07060302u);
}
// async global->LDS, 16B per lane: lane L writes lds_base + L*16
__device__ __forceinline__ void gload16(const u16* g, u16* l) {
    __builtin_amdgcn_global_load_lds(
        (const __attribute__((address_space(1))) void*)(u16*)g,
        (__attribute__((address_space(3))) void*)l, 16, 0, 0);
}

// ---------------------------------------------------------------------------
// K0a: straight fp32 -> bf16 convert (X)
// ---------------------------------------------------------------------------
__global__ __launch_bounds__(256) void cvt_kernel(
    const float* __restrict__ in, u16* __restrict__ out, int n4)
{
    const int i = blockIdx.x * 256 + threadIdx.x;
    if (i < n4) {
        float4 f = ((const float4*)in)[i];
        ushort4 r;
        r.x = f2bf(f.x); r.y = f2bf(f.y); r.z = f2bf(f.z); r.w = f2bf(f.w);
        ((ushort4*)out)[i] = r;
    }
}

// ---------------------------------------------------------------------------
// K0b: transpose-convert weights: fp32 [K][N] -> bf16 [N][K].
// ---------------------------------------------------------------------------
__global__ __launch_bounds__(256) void tw_kernel(
    const float* __restrict__ Wq, const float* __restrict__ Wk,
    const float* __restrict__ Wv, const float* __restrict__ Wo,
    u16* __restrict__ Tq, u16* __restrict__ Tk,
    u16* __restrict__ Tv, u16* __restrict__ To)
{
    __shared__ float tile[64][65];
    const int by = blockIdx.y;
    const float* W; u16* T; int N, n0;
    if (by < 32)      { W = Wq; T = Tq; N = 2048; n0 = by * 64; }
    else if (by < 40) { W = Wk; T = Tk; N = 512;  n0 = (by - 32) * 64; }
    else if (by < 48) { W = Wv; T = Tv; N = 512;  n0 = (by - 40) * 64; }
    else              { W = Wo; T = To; N = 2048; n0 = (by - 48) * 64; }
    const int k0 = blockIdx.x * 64;
    const int r  = threadIdx.x >> 2;
    const int c0 = (threadIdx.x & 3) << 4;
    #pragma unroll
    for (int u = 0; u < 4; ++u) {
        float4 f = *(const float4*)&W[(size_t)(k0 + r) * N + n0 + c0 + u * 4];
        tile[r][c0 + u * 4 + 0] = f.x; tile[r][c0 + u * 4 + 1] = f.y;
        tile[r][c0 + u * 4 + 2] = f.z; tile[r][c0 + u * 4 + 3] = f.w;
    }
    __syncthreads();
    #pragma unroll
    for (int u = 0; u < 4; ++u) {
        ushort4 o;
        o.x = f2bf(tile[c0 + u * 4 + 0][r]);
        o.y = f2bf(tile[c0 + u * 4 + 1][r]);
        o.z = f2bf(tile[c0 + u * 4 + 2][r]);
        o.w = f2bf(tile[c0 + u * 4 + 3][r]);
        *(ushort4*)&T[(size_t)(n0 + r) * HID + k0 + c0 + u * 4] = o;
    }
}

// ---------------------------------------------------------------------------
// K1: QKV projection, bf16 MFMA (16x16x32), 128x128x32 tile.
// Round-17: global_load_lds staging (linear LDS [128][32]) with both-sides
// XOR swizzle: lane fetches global slot (L&3)^(lrow&3); read slot lg^(l15&3).
// ---------------------------------------------------------------------------
__global__ __launch_bounds__(256) void proj_kernel(
    const u16* __restrict__ Xb,
    const u16* __restrict__ Tq, const u16* __restrict__ Tk, const u16* __restrict__ Tv,
    const float* __restrict__ bq, const float* __restrict__ bk, const float* __restrict__ bv,
    u16* __restrict__ qo, u16* __restrict__ ko, u16* __restrict__ vo)
{
    __shared__ __align__(16) u16 Al[128][32];
    __shared__ __align__(16) u16 Bl[128][32];
    const int tid = threadIdx.x;
    const int w = tid >> 6, l15 = tid & 15, lg = (tid & 63) >> 4;
    const int wr = w >> 1, wc = w & 1;
    const int m0 = blockIdx.x * 128;
    const int n0 = blockIdx.y * 128;

    const u16* Bt; const float* bias; u16* dst; int nh, nb;
    if (n0 < 2048)      { Bt = Tq + (size_t)n0 * HID;          bias = bq + n0;          dst = qo; nh = NH;  nb = n0; }
    else if (n0 < 2560) { Bt = Tk + (size_t)(n0 - 2048) * HID; bias = bk + (n0 - 2048); dst = ko; nh = NKV; nb = n0 - 2048; }
    else                { Bt = Tv + (size_t)(n0 - 2560) * HID; bias = bv + (n0 - 2560); dst = vo; nh = NKV; nb = n0 - 2560; }

    const int L    = tid & 63;
    const int lrow = L >> 2;                      // 0..15 within 16-row chunk
    const int sdat = (L & 3) ^ (lrow & 3);        // swizzled global slot
    const int arow = w * 32 + lrow;               // wave covers rows w*32..+31
    const int sw   = (lg ^ (l15 & 3)) * 8;        // swizzled read col (u16)

    f32x4 acc[4][4] = {};
    for (int k0 = 0; k0 < HID; k0 += 32) {
        gload16(&Xb[(size_t)(m0 + arow) * HID + k0 + sdat * 8],      &Al[w * 32][0]);
        gload16(&Xb[(size_t)(m0 + arow + 16) * HID + k0 + sdat * 8], &Al[w * 32 + 16][0]);
        gload16(&Bt[(size_t)(arow) * HID + k0 + sdat * 8],           &Bl[w * 32][0]);
        gload16(&Bt[(size_t)(arow + 16) * HID + k0 + sdat * 8],      &Bl[w * 32 + 16][0]);
        __syncthreads();   // compiler drains vmcnt before barrier -> tile ready
        bf16x8 af[4], bfr[4];
        #pragma unroll
        for (int i = 0; i < 4; ++i) {
            af[i]  = *(const bf16x8*)&Al[wr * 64 + i * 16 + l15][sw];
            bfr[i] = *(const bf16x8*)&Bl[wc * 64 + i * 16 + l15][sw];
        }
        #pragma unroll
        for (int mf = 0; mf < 4; ++mf)
            #pragma unroll
            for (int nf = 0; nf < 4; ++nf)
                acc[mf][nf] = __builtin_amdgcn_mfma_f32_16x16x32_bf16(af[mf], bfr[nf], acc[mf][nf], 0, 0, 0);
        __syncthreads();   // all reads done before next iteration's writes
    }

    #pragma unroll
    for (int nf = 0; nf < 4; ++nf) {
        const int cl = nb + wc * 64 + nf * 16 + l15;
        const int hh = cl >> 6, dd = cl & 63;
        const float bv_ = bias[wc * 64 + nf * 16 + l15];
        #pragma unroll
        for (int mf = 0; mf < 4; ++mf)
            #pragma unroll
            for (int r = 0; r < 4; ++r) {
                const int m = m0 + wr * 64 + mf * 16 + lg * 4 + r;
                const int bb_ = m >> 11, ss = m & (SS_ - 1);
                dst[(((size_t)bb_ * nh + hh) * SS_ + ss) * HD + dd] = f2bf(acc[mf][nf][r] + bv_);
            }
    }
}

// ---------------------------------------------------------------------------
// K2: flash attention (round-16 body, 324-us state) — UNCHANGED.
// ---------------------------------------------------------------------------
__global__ __launch_bounds__(512, 4) void attn_kernel(
    const u16* __restrict__ q, const u16* __restrict__ k,
    const u16* __restrict__ v, u16* __restrict__ o)
{
    union SMem {
        struct { u16 Ks[2][KT][LDK]; u16 Vt[2][HD][LDV]; } s;   // 35840 B
        u16 Ot[QT][LDO];                                        // 33792 B
    };
    __shared__ SMem sm;

    const int tid = threadIdx.x;
    const int w   = tid >> 6;        // 0..7
    const int l   = tid & 63;
    const int l31 = l & 31;
    const int hi  = l >> 5;
    const int qt  = blockIdx.x;
    const int h   = blockIdx.y;
    const int b   = blockIdx.z;
    const int hk  = h >> 2;

    const u16* qb = q + (((size_t)b * NH  + h ) * SS_ + qt * QT) * HD;
    const u16* kp = k + (((size_t)b * NKV + hk) * SS_) * HD;
    const u16* vp = v + (((size_t)b * NKV + hk) * SS_) * HD;

    bf16x8 qf[4];
    #pragma unroll
    for (int kc = 0; kc < 4; ++kc)
        qf[kc] = *(const bf16x8*)&qb[(size_t)(w * 32 + l31) * HD + kc * 16 + hi * 8];

    f32x16 oaccT[2] = {};
    float d0s = 0.f, d1s = 0.f, d2s = 0.f, d3s = 0.f;
    const float C = 0.1803368801f;   // 0.125 * log2(e)

    const int krow = tid >> 3, kcol = (tid & 7) << 3;
    const int vk0  = (tid & 31) << 1, vd0 = (tid >> 5) << 2;

    const int NT = SS_ / KT;

    {
        bf16x8 kr0 = *(const bf16x8*)&kp[(size_t)krow * HD + kcol];
        uint2 vv[2];
        #pragma unroll
        for (int i = 0; i < 2; ++i)
            vv[i] = *(const uint2*)&vp[(size_t)(vk0 + i) * HD + vd0];
        *(bf16x8*)&sm.s.Ks[0][krow][kcol] = kr0;
        #pragma unroll
        for (int j = 0; j < 4; ++j) {
            ushort2 tv;
            tv.x = ((const u16*)&vv[0])[j];
            tv.y = ((const u16*)&vv[1])[j];
            *(ushort2*)&sm.s.Vt[0][vd0 + j][vk0] = tv;
        }
    }
    __syncthreads();

    int p = 0;
    for (int t = 0; t < NT; ++t) {
        const int tn = (t + 1 < NT) ? (t + 1) : (NT - 1);
        bf16x8 nk0 = *(const bf16x8*)&kp[(size_t)(tn * KT + krow) * HD + kcol];
        uint2 nv[2];
        #pragma unroll
        for (int i = 0; i < 2; ++i)
            nv[i] = *(const uint2*)&vp[(size_t)(tn * KT + vk0 + i) * HD + vd0];

        f32x16 st[2] = {};
        __builtin_amdgcn_s_setprio(1);
        #pragma unroll
        for (int kb = 0; kb < 2; ++kb)
            #pragma unroll
            for (int kc = 0; kc < 4; ++kc) {
                bf16x8 kf = *(const bf16x8*)&sm.s.Ks[p][kb * 32 + l31][kc * 16 + hi * 8];
                st[kb] = __builtin_amdgcn_mfma_f32_32x32x16_bf16(kf, qf[kc], st[kb], 0, 0, 0);
            }
        __builtin_amdgcn_s_setprio(0);

        #pragma unroll
        for (int kb = 0; kb < 2; ++kb)
            #pragma unroll
            for (int r = 0; r < 16; r += 4) {
                const float p0 = exp2f(st[kb][r + 0] * C);
                const float p1 = exp2f(st[kb][r + 1] * C);
                const float p2 = exp2f(st[kb][r + 2] * C);
                const float p3 = exp2f(st[kb][r + 3] * C);
                st[kb][r + 0] = p0; st[kb][r + 1] = p1;
                st[kb][r + 2] = p2; st[kb][r + 3] = p3;
                d0s += p0; d1s += p1; d2s += p2; d3s += p3;
            }

        #pragma unroll
        for (int kc = 0; kc < 4; ++kc) {
            const int kb = kc >> 1, c4 = (kc & 1) * 4;
            const unsigned int a0 = pack_rtz(st[kb][2 * (c4 + 0)], st[kb][2 * (c4 + 0) + 1]);
            const unsigned int a1 = pack_rtz(st[kb][2 * (c4 + 1)], st[kb][2 * (c4 + 1) + 1]);
            const unsigned int a2 = pack_rtz(st[kb][2 * (c4 + 2)], st[kb][2 * (c4 + 2) + 1]);
            const unsigned int a3 = pack_rtz(st[kb][2 * (c4 + 3)], st[kb][2 * (c4 + 3) + 1]);
            u32x2 r0 = __builtin_amdgcn_permlane32_swap(a0, a2, false, false);
            u32x2 r1 = __builtin_amdgcn_permlane32_swap(a1, a3, false, false);
            uint4 pbu;
            pbu.x = r0.x;
            pbu.y = r1.x;
            pbu.z = r0.y;
            pbu.w = r1.y;
            bf16x8 pb = *(bf16x8*)&pbu;
            __builtin_amdgcn_s_setprio(1);
            #pragma unroll
            for (int db = 0; db < 2; ++db) {
                bf16x8 vf = *(const bf16x8*)&sm.s.Vt[p][db * 32 + l31][kc * 16 + hi * 8];
                oaccT[db] = __builtin_amdgcn_mfma_f32_32x32x16_bf16(vf, pb, oaccT[db], 0, 0, 0);
            }
            __builtin_amdgcn_s_setprio(0);
        }

        if (t + 1 < NT) {
            *(bf16x8*)&sm.s.Ks[p ^ 1][krow][kcol] = nk0;
            #pragma unroll
            for (int j = 0; j < 4; ++j) {
                ushort2 tv;
                tv.x = ((const u16*)&nv[0])[j];
                tv.y = ((const u16*)&nv[1])[j];
                *(ushort2*)&sm.s.Vt[p ^ 1][vd0 + j][vk0] = tv;
            }
        }
        __syncthreads();
        p ^= 1;
    }

    float l_i = (d0s + d1s) + (d2s + d3s);
    l_i += __shfl_xor(l_i, 32);
    const float inv = 1.0f / l_i;

    #pragma unroll
    for (int db = 0; db < 2; ++db)
        #pragma unroll
        for (int pp = 0; pp < 8; ++pp) {
            const int d0 = db * 32 + 2 * (pp & 1) + 4 * hi + 8 * (pp >> 1);
            unsigned int r_ = pack_bf2(oaccT[db][2 * pp] * inv, oaccT[db][2 * pp + 1] * inv);
            *(unsigned int*)&sm.Ot[w * 32 + l31][d0] = r_;
        }
    __syncthreads();
    {
        const int row = tid >> 1, half = tid & 1;
        u16* go = o + ((size_t)b * SS_ + qt * QT + row) * HID + h * HD + half * 32;
        #pragma unroll
        for (int u = 0; u < 2; ++u) {
            uint4 t0 = *(uint4*)&sm.Ot[row][half * 32 + u * 16];
            *(uint4*)&go[u * 16] = t0;
            uint4 t1 = *(uint4*)&sm.Ot[row][half * 32 + u * 16 + 8];
            *(uint4*)&go[u * 16 + 8] = t1;
        }
    }
}

// ---------------------------------------------------------------------------
// K3: output projection — same global_load_lds + XOR-swizzle staging.
// ---------------------------------------------------------------------------
__global__ __launch_bounds__(256) void oproj_kernel(
    const u16* __restrict__ Ab, const u16* __restrict__ To,
    const float* __restrict__ bo, float* __restrict__ out)
{
    __shared__ __align__(16) u16 Al[128][32];
    __shared__ __align__(16) u16 Bl[128][32];
    const int tid = threadIdx.x;
    const int w = tid >> 6, l15 = tid & 15, lg = (tid & 63) >> 4;
    const int wr = w >> 1, wc = w & 1;
    const int m0 = blockIdx.x * 128;
    const int n0 = blockIdx.y * 128;
    const u16* Bt = To + (size_t)n0 * HID;

    const int L    = tid & 63;
    const int lrow = L >> 2;
    const int sdat = (L & 3) ^ (lrow & 3);
    const int arow = w * 32 + lrow;
    const int sw   = (lg ^ (l15 & 3)) * 8;

    f32x4 acc[4][4] = {};
    for (int k0 = 0; k0 < HID; k0 += 32) {
        gload16(&Ab[(size_t)(m0 + arow) * HID + k0 + sdat * 8],      &Al[w * 32][0]);
        gload16(&Ab[(size_t)(m0 + arow + 16) * HID + k0 + sdat * 8], &Al[w * 32 + 16][0]);
        gload16(&Bt[(size_t)(arow) * HID + k0 + sdat * 8],           &Bl[w * 32][0]);
        gload16(&Bt[(size_t)(arow + 16) * HID + k0 + sdat * 8],      &Bl[w * 32 + 16][0]);
        __syncthreads();
        bf16x8 af[4], bfr[4];
        #pragma unroll
        for (int i = 0; i < 4; ++i) {
            af[i]  = *(const bf16x8*)&Al[wr * 64 + i * 16 + l15][sw];
            bfr[i] = *(const bf16x8*)&Bl[wc * 64 + i * 16 + l15][sw];
        }
        #pragma unroll
        for (int mf = 0; mf < 4; ++mf)
            #pragma unroll
            for (int nf = 0; nf < 4; ++nf)
                acc[mf][nf] = __builtin_amdgcn_mfma_f32_16x16x32_bf16(af[mf], bfr[nf], acc[mf][nf], 0, 0, 0);
        __syncthreads();
    }

    #pragma unroll
    for (int nf = 0; nf < 4; ++nf) {
        const int col = n0 + wc * 64 + nf * 16 + l15;
        const float bv_ = bo[col];
        #pragma unroll
        for (int mf = 0; mf < 4; ++mf)
            #pragma unroll
            for (int r = 0; r < 4; ++r) {
                const int m = m0 + wr * 64 + mf * 16 + lg * 4 + r;
                out[(size_t)m * HID + col] = acc[mf][nf][r] + bv_;
            }
    }
}

// ---------------------------------------------------------------------------
extern "C" void kernel_launch(void* const* d_in, const int* in_sizes, int n_in,
                              void* d_out, int out_size, void* d_ws, size_t ws_size,
                              hipStream_t stream) {
    int iX = 0, iWq = 1, ibq = 2, iWk = 3, ibk = 4, iWv = 5, ibv = 6, iWo = 7, ibo = 8;
    if (n_in == 9 && in_sizes[1] == 1048576) {   // alphabetical-order hedge
        iWk = 1; iWo = 2; iWq = 3; iWv = 4; ibk = 5; ibo = 6; ibq = 7; ibv = 8;
    }
    const float* X  = (const float*)d_in[iX];
    const float* Wq = (const float*)d_in[iWq];
    const float* bq = (const float*)d_in[ibq];
    const float* Wk = (const float*)d_in[iWk];
    const float* bk = (const float*)d_in[ibk];
    const float* Wv = (const float*)d_in[iWv];
    const float* bv = (const float*)d_in[ibv];
    const float* Wo = (const float*)d_in[iWo];
    const float* bo = (const float*)d_in[ibo];
    float* out = (float*)d_out;

    u16* Xb  = (u16*)d_ws;                                  // [4096][2048]
    u16* Tq  = Xb  + (size_t)MM * HID;                      // [2048][2048]
    u16* Tk  = Tq  + (size_t)HID * HID;                     // [512][2048]
    u16* Tv  = Tk  + (size_t)512 * HID;                     // [512][2048]
    u16* To  = Tv  + (size_t)512 * HID;                     // [2048][2048]
    u16* qws = To  + (size_t)HID * HID;                     // [2,32,2048,64]
    u16* kws = qws + (size_t)BB * NH  * SS_ * HD;           // [2,8,2048,64]
    u16* vws = kws + (size_t)BB * NKV * SS_ * HD;           // [2,8,2048,64]
    u16* ows = vws + (size_t)BB * NKV * SS_ * HD;           // [4096][2048]

    cvt_kernel<<<dim3((MM * HID / 4 + 255) / 256), 256, 0, stream>>>(X, Xb, MM * HID / 4);
    tw_kernel<<<dim3(32, 80), 256, 0, stream>>>(Wq, Wk, Wv, Wo, Tq, Tk, Tv, To);
    proj_kernel<<<dim3(32, 24), 256, 0, stream>>>(Xb, Tq, Tk, Tv, bq, bk, bv, qws, kws, vws);
    attn_kernel<<<dim3(SS_ / QT, 32, 2), 512, 0, stream>>>(qws, kws, vws, ows);
    oproj_kernel<<<dim3(32, 16), 256, 0, stream>>>(ows, To, bo, out);
}